// Round 1
// baseline (6037.169 us; speedup 1.0000x reference)
//
#include <hip/hip_runtime.h>

#define V 49152
#define B 4
#define T 8
#define FIN 32
#define FOUT 64
#define KCH 3
#define TW 3
#define NNZ (9 * V)
#define EPS 1e-5f

// ws layout (floats):
// [0, 50331648)            x1  : [V][B*T*FIN] layout v*1024 + b*256 + t*32 + f
// [50331648, 100663296)    x2  : same layout
// [100663296, +256)        stats: sum[64] | sumsq[64] | scale[64] | shift[64]
#define X2_OFF 50331648LL
#define ST_OFF 100663296LL

// ---------------------------------------------------------------- SpMM 1: x1 += L * x0
__global__ void spmm1_kernel(const float* __restrict__ x, const float* __restrict__ vals,
                             const int* __restrict__ rows, const int* __restrict__ cols,
                             float* __restrict__ x1) {
    int gid = blockIdx.x * 256 + threadIdx.x;
    int e = gid >> 10;
    if (e >= NNZ) return;
    int j = gid & 1023;           // b*256 + t*32 + f
    int c = cols[e], r = rows[e];
    float val = vals[e];
    int b = j >> 8, tf = j & 255;
    float s = x[(b * V + c) * 256 + tf];      // gather from original x layout [B][V][T][FIN]
    atomicAdd(&x1[r * 1024 + j], val * s);
}

// ---------------------------------------------------------------- x2 = -x0 (init before SpMM 2)
__global__ void init_x2_kernel(const float* __restrict__ x, float* __restrict__ x2) {
    int gid = blockIdx.x * 256 + threadIdx.x;   // < V*1024
    int v = gid >> 10, j = gid & 1023;
    int b = j >> 8, tf = j & 255;
    x2[gid] = -x[(b * V + v) * 256 + tf];
}

// ---------------------------------------------------------------- SpMM 2: x2 += 2 * L * x1
__global__ void spmm2_kernel(const float* __restrict__ x1, const float* __restrict__ vals,
                             const int* __restrict__ rows, const int* __restrict__ cols,
                             float* __restrict__ x2) {
    int gid = blockIdx.x * 256 + threadIdx.x;
    int e = gid >> 10;
    if (e >= NNZ) return;
    int j = gid & 1023;
    int c = cols[e], r = rows[e];
    float val = vals[e];
    float s = x1[c * 1024 + j];
    atomicAdd(&x2[r * 1024 + j], 2.0f * val * s);
}

// ---------------------------------------------------------------- dense contraction (im2col conv)
// block = 64 threads (one wave, lane = output channel o); grid = (V, B)
// each thread accumulates all T=8 time outputs so every W load feeds 8 FMAs.
__global__ __launch_bounds__(64)
void dense_kernel(const float* __restrict__ x, const float* __restrict__ x1,
                  const float* __restrict__ x2, const float* __restrict__ W,
                  float* __restrict__ y) {
    __shared__ float xs[3 * 256];     // xk[k][t'][f]
    int v = blockIdx.x, b = blockIdx.y;
    int tid = threadIdx.x;

    #pragma unroll
    for (int i = 0; i < 12; ++i) {
        int idx = tid + 64 * i;       // 0..767
        int k = idx >> 8, tf = idx & 255;
        float val;
        if (k == 0)      val = x [(b * V + v) * 256 + tf];
        else if (k == 1) val = x1[v * 1024 + b * 256 + tf];
        else             val = x2[v * 1024 + b * 256 + tf];
        xs[idx] = val;
    }
    __syncthreads();

    float acc[T];
    #pragma unroll
    for (int t = 0; t < T; ++t) acc[t] = 0.f;
    int o = tid;

    for (int k = 0; k < KCH; ++k) {
        const float* xk = &xs[k * 256];
        #pragma unroll
        for (int tw = 0; tw < TW; ++tw) {
            const float* wp = &W[((k * TW + tw) * FIN) * FOUT + o];
            for (int f = 0; f < FIN; ++f) {
                float w = wp[f * FOUT];
                #pragma unroll
                for (int t = 0; t < T; ++t) {
                    int tp = t + tw - 1;               // folds at compile time (tw,t unrolled)
                    if (tp >= 0 && tp < T)
                        acc[t] = fmaf(xk[tp * 32 + f], w, acc[t]);
                }
            }
        }
    }

    #pragma unroll
    for (int t = 0; t < T; ++t)
        y[((b * V + v) * T + t) * FOUT + o] = acc[t];   // pre-BN activations (bias cancels in BN)
}

// ---------------------------------------------------------------- BN stats: per-channel sum & sumsq
__global__ void stats_kernel(const float* __restrict__ y, float* __restrict__ stats) {
    __shared__ float s_sum[256], s_sq[256];
    const int total = B * V * T * FOUT;   // 100,663,296
    int o = threadIdx.x & 63;
    float sum = 0.f, sq = 0.f;
    for (int i = blockIdx.x * 256 + threadIdx.x; i < total; i += gridDim.x * 256) {
        float val = y[i];                 // i % 64 == o (all strides are multiples of 64)
        sum += val; sq += val * val;
    }
    s_sum[threadIdx.x] = sum; s_sq[threadIdx.x] = sq;
    __syncthreads();
    if (threadIdx.x < 64) {
        sum = s_sum[threadIdx.x] + s_sum[threadIdx.x + 64] + s_sum[threadIdx.x + 128] + s_sum[threadIdx.x + 192];
        sq  = s_sq [threadIdx.x] + s_sq [threadIdx.x + 64] + s_sq [threadIdx.x + 128] + s_sq [threadIdx.x + 192];
        atomicAdd(&stats[o], sum);
        atomicAdd(&stats[64 + o], sq);
    }
}

// ---------------------------------------------------------------- fold mean/var/gamma/beta -> scale/shift
__global__ void finalize_kernel(const float* __restrict__ gamma, const float* __restrict__ beta,
                                float* __restrict__ stats) {
    int o = threadIdx.x;   // 64 threads
    float n = (float)(B * V * T);
    float mean = stats[o] / n;
    float var = stats[64 + o] / n - mean * mean;
    float sc = gamma[o] * rsqrtf(var + EPS);
    stats[128 + o] = sc;
    stats[192 + o] = beta[o] - mean * sc;
}

// ---------------------------------------------------------------- normalize + ReLU (in place on d_out)
__global__ void norm_kernel(float* __restrict__ y, const float* __restrict__ stats) {
    const int total = B * V * T * FOUT;
    for (int i = blockIdx.x * 256 + threadIdx.x; i < total; i += gridDim.x * 256) {
        int o = i & 63;
        float val = y[i] * stats[128 + o] + stats[192 + o];
        y[i] = fmaxf(val, 0.f);
    }
}

extern "C" void kernel_launch(void* const* d_in, const int* in_sizes, int n_in,
                              void* d_out, int out_size, void* d_ws, size_t ws_size,
                              hipStream_t stream) {
    const float* x        = (const float*)d_in[0];
    const float* lap_vals = (const float*)d_in[1];
    const float* W        = (const float*)d_in[2];
    // d_in[3] = bias: cancels exactly under training-mode BN, unused
    const float* gamma    = (const float*)d_in[4];
    const float* beta     = (const float*)d_in[5];
    const int*   rows     = (const int*)d_in[6];
    const int*   cols     = (const int*)d_in[7];
    float* out = (float*)d_out;
    float* ws  = (float*)d_ws;

    float* x1    = ws;
    float* x2    = ws + X2_OFF;
    float* stats = ws + ST_OFF;

    hipMemsetAsync(x1, 0, (size_t)X2_OFF * sizeof(float), stream);
    hipMemsetAsync(stats, 0, 256 * sizeof(float), stream);

    spmm1_kernel<<<NNZ * 4, 256, 0, stream>>>(x, lap_vals, rows, cols, x1);
    init_x2_kernel<<<V * 4, 256, 0, stream>>>(x, x2);
    spmm2_kernel<<<NNZ * 4, 256, 0, stream>>>(x1, lap_vals, rows, cols, x2);
    dense_kernel<<<dim3(V, B), 64, 0, stream>>>(x, x1, x2, W, out);
    stats_kernel<<<1024, 256, 0, stream>>>(out, stats);
    finalize_kernel<<<1, 64, 0, stream>>>(gamma, beta, stats);
    norm_kernel<<<2048, 256, 0, stream>>>(out, stats);
}

// Round 2
// 1048.349 us; speedup vs baseline: 5.7587x; 5.7587x over previous
//
#include <hip/hip_runtime.h>

#define V 49152
#define B 4
#define T 8
#define FIN 32
#define FOUT 64
#define NNZ (9 * V)
#define EPS 1e-5f

typedef __attribute__((ext_vector_type(8))) short bf16x8;
typedef __attribute__((ext_vector_type(4))) float f32x4;
typedef __attribute__((ext_vector_type(4))) float float4v;
typedef __attribute__((ext_vector_type(8))) unsigned short u16x8;
typedef __attribute__((ext_vector_type(4))) unsigned short u16x4;

// ---------------- ws layout (bytes) ----------------
// x0b/x1b/x2b: bf16 [V][B*T*FIN]  (v*1024 + b*256 + t*32 + f)
#define X0B_OFF 0LL
#define X1B_OFF 100663296LL
#define X2B_OFF 201326592LL
#define STATS_OFF 301989888LL            // 256 floats
#define CNT_OFF 301990912LL              // V ints
#define CURS_OFF 302187520LL             // V ints
#define OFFS_OFF 302384128LL             // V+1 ints
#define CSRC_OFF 302580752LL             // NNZ ints
#define CSRV_OFF 304350224LL             // NNZ floats
// memset range: STATS..OFFS start covers stats+cnt+cursor
#define ZERO_BYTES (302384128LL - 301989888LL)

__device__ inline unsigned short f2bf(float f) {
    unsigned u = __builtin_bit_cast(unsigned, f);
    u += 0x7fffu + ((u >> 16) & 1u);
    return (unsigned short)(u >> 16);
}
__device__ inline float bf2f(unsigned short h) {
    return __builtin_bit_cast(float, ((unsigned)h) << 16);
}

// ---------------- convert x fp32 [B][V][T*F] -> bf16 [V][B][T*F] ----------------
__global__ __launch_bounds__(256)
void convert_kernel(const float* __restrict__ x, unsigned short* __restrict__ x0b) {
    unsigned gid = blockIdx.x * 256 + threadIdx.x;     // 6,291,456 threads, 8 elems each
    unsigned idx = gid * 8;
    unsigned j = idx & 255;
    unsigned bv = idx >> 8;
    unsigned b = bv / V;
    unsigned v = bv - b * V;
    const float4v* src = (const float4v*)(x + idx);
    float4v f0 = src[0], f1 = src[1];
    u16x8 o;
    o[0] = f2bf(f0[0]); o[1] = f2bf(f0[1]); o[2] = f2bf(f0[2]); o[3] = f2bf(f0[3]);
    o[4] = f2bf(f1[0]); o[5] = f2bf(f1[1]); o[6] = f2bf(f1[2]); o[7] = f2bf(f1[3]);
    *(u16x8*)(x0b + v * 1024 + b * 256 + j) = o;
}

// ---------------- CSR build ----------------
__global__ __launch_bounds__(256)
void count_kernel(const int* __restrict__ rows, int* __restrict__ cnt) {
    int e = blockIdx.x * 256 + threadIdx.x;
    if (e < NNZ) atomicAdd(&cnt[rows[e]], 1);
}

__global__ __launch_bounds__(1024)
void scan_kernel(const int* __restrict__ cnt, int* __restrict__ offs) {
    __shared__ int s[1024];
    __shared__ int carry;
    if (threadIdx.x == 0) carry = 0;
    __syncthreads();
    for (int base = 0; base < V; base += 1024) {
        int val = cnt[base + threadIdx.x];
        s[threadIdx.x] = val;
        __syncthreads();
        for (int off = 1; off < 1024; off <<= 1) {
            int add = (threadIdx.x >= off) ? s[threadIdx.x - off] : 0;
            __syncthreads();
            s[threadIdx.x] += add;
            __syncthreads();
        }
        int incl = s[threadIdx.x];
        offs[base + threadIdx.x + 1] = carry + incl;
        __syncthreads();
        if (threadIdx.x == 1023) carry += incl;
        __syncthreads();
    }
    if (threadIdx.x == 0) offs[0] = 0;
}

__global__ __launch_bounds__(256)
void scatter_kernel(const int* __restrict__ rows, const int* __restrict__ cols,
                    const float* __restrict__ vals, const int* __restrict__ offs,
                    int* __restrict__ cursor, int* __restrict__ csr_c, float* __restrict__ csr_v) {
    int e = blockIdx.x * 256 + threadIdx.x;
    if (e < NNZ) {
        int r = rows[e];
        int p = offs[r] + atomicAdd(&cursor[r], 1);
        csr_c[p] = cols[e];
        csr_v[p] = vals[e];
    }
}

// ---------------- SpMM 1: x1 = L @ x0 (CSR rows, fp32 acc, bf16 io) ----------------
__global__ __launch_bounds__(256)
void spmm1_kernel(const unsigned short* __restrict__ x0b, const int* __restrict__ offs,
                  const int* __restrict__ csr_c, const float* __restrict__ csr_v,
                  unsigned short* __restrict__ x1b) {
    int r = blockIdx.x;
    int j = threadIdx.x * 4;
    int e0 = offs[r], e1 = offs[r + 1];
    float s0 = 0.f, s1 = 0.f, s2 = 0.f, s3 = 0.f;
    for (int e = e0; e < e1; ++e) {
        int c = csr_c[e];
        float val = csr_v[e];
        u16x4 xv = *(const u16x4*)(x0b + c * 1024 + j);
        s0 = fmaf(val, bf2f(xv[0]), s0);
        s1 = fmaf(val, bf2f(xv[1]), s1);
        s2 = fmaf(val, bf2f(xv[2]), s2);
        s3 = fmaf(val, bf2f(xv[3]), s3);
    }
    u16x4 o;
    o[0] = f2bf(s0); o[1] = f2bf(s1); o[2] = f2bf(s2); o[3] = f2bf(s3);
    *(u16x4*)(x1b + r * 1024 + j) = o;
}

// ---------------- SpMM 2: x2 = 2 * (L @ x1) - x0 ----------------
__global__ __launch_bounds__(256)
void spmm2_kernel(const unsigned short* __restrict__ x0b, const unsigned short* __restrict__ x1b,
                  const int* __restrict__ offs, const int* __restrict__ csr_c,
                  const float* __restrict__ csr_v, unsigned short* __restrict__ x2b) {
    int r = blockIdx.x;
    int j = threadIdx.x * 4;
    int e0 = offs[r], e1 = offs[r + 1];
    float s0 = 0.f, s1 = 0.f, s2 = 0.f, s3 = 0.f;
    for (int e = e0; e < e1; ++e) {
        int c = csr_c[e];
        float val = csr_v[e];
        u16x4 xv = *(const u16x4*)(x1b + c * 1024 + j);
        s0 = fmaf(val, bf2f(xv[0]), s0);
        s1 = fmaf(val, bf2f(xv[1]), s1);
        s2 = fmaf(val, bf2f(xv[2]), s2);
        s3 = fmaf(val, bf2f(xv[3]), s3);
    }
    u16x4 xv0 = *(const u16x4*)(x0b + r * 1024 + j);
    u16x4 o;
    o[0] = f2bf(2.f * s0 - bf2f(xv0[0]));
    o[1] = f2bf(2.f * s1 - bf2f(xv0[1]));
    o[2] = f2bf(2.f * s2 - bf2f(xv0[2]));
    o[3] = f2bf(2.f * s3 - bf2f(xv0[3]));
    *(u16x4*)(x2b + r * 1024 + j) = o;
}

// ---------------- dense contraction via MFMA ----------------
// Per v: C[32 rows=(b*8+t)][64 cols=o] = A[32][288] @ W2[288][64]
// K-chunk kc = (kk*3+tw); A frag = xk_kk[v][b][t+tw-1][f0..f0+8] (zero pad in t')
// 16 v per block, 4 waves (4 v per wave). W2^T staged in LDS as wt[64][296] bf16.
#define VPB 16
__global__ __launch_bounds__(256)
void dense_kernel(const unsigned short* __restrict__ x0b, const unsigned short* __restrict__ x1b,
                  const unsigned short* __restrict__ x2b, const float* __restrict__ W,
                  float* __restrict__ y) {
    __shared__ short wt[64 * 296];
    for (int idx = threadIdx.x; idx < 288 * 64; idx += 256) {
        int k = idx >> 6, o = idx & 63;
        wt[o * 296 + k] = (short)f2bf(W[idx]);
    }
    __syncthreads();

    int wave = threadIdx.x >> 6;
    int lane = threadIdx.x & 63;
    int l15 = lane & 15, lhi = lane >> 4;
    int f0 = lhi * 8;
    int vbase = blockIdx.x * VPB + wave * (VPB / 4);

    for (int vi = 0; vi < VPB / 4; ++vi) {
        int v = vbase + vi;
        // load 18 A fragments (2 mtiles x 9 kchunks)
        bf16x8 afrag[2][9];
        #pragma unroll
        for (int mt = 0; mt < 2; ++mt) {
            int m = mt * 16 + l15;
            int b = m >> 3, t = m & 7;
            #pragma unroll
            for (int kc = 0; kc < 9; ++kc) {
                const int kk = kc / 3, tw = kc % 3;
                const int tp = t + tw - 1;
                const unsigned short* src = (kk == 0) ? x0b : (kk == 1) ? x1b : x2b;
                bf16x8 a = {0, 0, 0, 0, 0, 0, 0, 0};
                if ((unsigned)tp < 8u)
                    a = *(const bf16x8*)(src + v * 1024 + b * 256 + tp * 32 + f0);
                afrag[mt][kc] = a;
            }
        }
        f32x4 acc[2][4];
        #pragma unroll
        for (int mt = 0; mt < 2; ++mt)
            #pragma unroll
            for (int nt = 0; nt < 4; ++nt)
                acc[mt][nt] = (f32x4){0.f, 0.f, 0.f, 0.f};

        #pragma unroll
        for (int kc = 0; kc < 9; ++kc) {
            #pragma unroll
            for (int nt = 0; nt < 4; ++nt) {
                int n = nt * 16 + l15;
                bf16x8 bfrag = *(const bf16x8*)&wt[n * 296 + kc * 32 + f0];
                #pragma unroll
                for (int mt = 0; mt < 2; ++mt)
                    acc[mt][nt] = __builtin_amdgcn_mfma_f32_16x16x32_bf16(
                        afrag[mt][kc], bfrag, acc[mt][nt], 0, 0, 0);
            }
        }
        // write C: row m=(lhi*4+i)+mt*16 -> (b,t); col = nt*16+l15
        #pragma unroll
        for (int mt = 0; mt < 2; ++mt)
            #pragma unroll
            for (int nt = 0; nt < 4; ++nt)
                #pragma unroll
                for (int i = 0; i < 4; ++i) {
                    int m = mt * 16 + lhi * 4 + i;
                    int b = m >> 3, t = m & 7;
                    int col = nt * 16 + l15;
                    y[((b * V + v) * 8 + t) * 64 + col] = acc[mt][nt][i];
                }
    }
}

// ---------------- BN stats ----------------
__global__ __launch_bounds__(256)
void stats_kernel(const float* __restrict__ y, float* __restrict__ stats) {
    __shared__ float s_sum[256], s_sq[256];
    const int total = B * V * T * FOUT;
    int o = threadIdx.x & 63;
    float sum = 0.f, sq = 0.f;
    for (int i = blockIdx.x * 256 + threadIdx.x; i < total; i += gridDim.x * 256) {
        float val = y[i];
        sum += val; sq += val * val;
    }
    s_sum[threadIdx.x] = sum; s_sq[threadIdx.x] = sq;
    __syncthreads();
    if (threadIdx.x < 64) {
        sum = s_sum[threadIdx.x] + s_sum[threadIdx.x + 64] + s_sum[threadIdx.x + 128] + s_sum[threadIdx.x + 192];
        sq  = s_sq [threadIdx.x] + s_sq [threadIdx.x + 64] + s_sq [threadIdx.x + 128] + s_sq [threadIdx.x + 192];
        atomicAdd(&stats[o], sum);
        atomicAdd(&stats[64 + o], sq);
    }
}

__global__ __launch_bounds__(64)
void finalize_kernel(const float* __restrict__ gamma, const float* __restrict__ beta,
                     float* __restrict__ stats) {
    int o = threadIdx.x;
    float n = (float)(B * V * T);
    float mean = stats[o] / n;
    float var = stats[64 + o] / n - mean * mean;
    float sc = gamma[o] * rsqrtf(var + EPS);
    stats[128 + o] = sc;
    stats[192 + o] = beta[o] - mean * sc;
}

__global__ __launch_bounds__(256)
void norm_kernel(float* __restrict__ y, const float* __restrict__ stats) {
    const int total = B * V * T * FOUT;
    for (int i = blockIdx.x * 256 + threadIdx.x; i < total; i += gridDim.x * 256) {
        int o = i & 63;
        float val = y[i] * stats[128 + o] + stats[192 + o];
        y[i] = fmaxf(val, 0.f);
    }
}

extern "C" void kernel_launch(void* const* d_in, const int* in_sizes, int n_in,
                              void* d_out, int out_size, void* d_ws, size_t ws_size,
                              hipStream_t stream) {
    const float* x        = (const float*)d_in[0];
    const float* lap_vals = (const float*)d_in[1];
    const float* W        = (const float*)d_in[2];
    // d_in[3] = bias: cancels exactly under training-mode BN
    const float* gamma    = (const float*)d_in[4];
    const float* beta     = (const float*)d_in[5];
    const int*   rows     = (const int*)d_in[6];
    const int*   cols     = (const int*)d_in[7];
    float* out = (float*)d_out;
    char*  ws  = (char*)d_ws;

    unsigned short* x0b = (unsigned short*)(ws + X0B_OFF);
    unsigned short* x1b = (unsigned short*)(ws + X1B_OFF);
    unsigned short* x2b = (unsigned short*)(ws + X2B_OFF);
    float* stats = (float*)(ws + STATS_OFF);
    int*   cnt   = (int*)(ws + CNT_OFF);
    int*   curs  = (int*)(ws + CURS_OFF);
    int*   offs  = (int*)(ws + OFFS_OFF);
    int*   csr_c = (int*)(ws + CSRC_OFF);
    float* csr_v = (float*)(ws + CSRV_OFF);

    hipMemsetAsync(ws + STATS_OFF, 0, (size_t)ZERO_BYTES, stream);

    convert_kernel<<<24576, 256, 0, stream>>>(x, x0b);
    count_kernel<<<(NNZ + 255) / 256, 256, 0, stream>>>(rows, cnt);
    scan_kernel<<<1, 1024, 0, stream>>>(cnt, offs);
    scatter_kernel<<<(NNZ + 255) / 256, 256, 0, stream>>>(rows, cols, lap_vals, offs, curs, csr_c, csr_v);
    spmm1_kernel<<<V, 256, 0, stream>>>(x0b, offs, csr_c, csr_v, x1b);
    spmm2_kernel<<<V, 256, 0, stream>>>(x0b, x1b, offs, csr_c, csr_v, x2b);
    dense_kernel<<<V / VPB, 256, 0, stream>>>(x0b, x1b, x2b, W, out);
    stats_kernel<<<1024, 256, 0, stream>>>(out, stats);
    finalize_kernel<<<1, 64, 0, stream>>>(gamma, beta, stats);
    norm_kernel<<<2048, 256, 0, stream>>>(out, stats);
}

// Round 3
// 771.690 us; speedup vs baseline: 7.8233x; 1.3585x over previous
//
#include <hip/hip_runtime.h>

#define V 49152
#define B 4
#define T 8
#define NNZ (9 * V)
#define EPS 1e-5f
#define SLOTS 32

typedef __attribute__((ext_vector_type(8))) short bf16x8;
typedef __attribute__((ext_vector_type(4))) float f32x4;
typedef __attribute__((ext_vector_type(4))) float float4v;
typedef __attribute__((ext_vector_type(8))) unsigned short u16x8;
typedef __attribute__((ext_vector_type(4))) unsigned short u16x4;

// ---------------- ws layout (bytes) ----------------
#define STATS_OFF 0LL          // 256 floats: sum[64]|sumsq[64]|scale[64]|shift[64]
#define CNT_OFF   1024LL       // V ints
#define CSRC_OFF  197632LL     // V*SLOTS ints   (memset covers [0, CSRC_OFF))
#define CSRV_OFF  6489088LL    // V*SLOTS floats
#define X0B_OFF   12780544LL   // V*1024 bf16
#define X1B_OFF   113443840LL  // V*1024 bf16
#define YB_OFF    214107136LL  // B*V*T*64 bf16 (only if ws is big enough)
#define WS_NEED_YB 415433728LL

__device__ inline unsigned short f2bf(float f) {
    unsigned u = __builtin_bit_cast(unsigned, f);
    u += 0x7fffu + ((u >> 16) & 1u);
    return (unsigned short)(u >> 16);
}
__device__ inline float bf2f(unsigned short h) {
    return __builtin_bit_cast(float, ((unsigned)h) << 16);
}

// ---------------- convert x fp32 [B][V][T*F] -> bf16 [V][B][T*F] ----------------
__global__ __launch_bounds__(256)
void convert_kernel(const float* __restrict__ x, unsigned short* __restrict__ x0b) {
    unsigned gid = blockIdx.x * 256 + threadIdx.x;
    unsigned idx = gid * 8;
    unsigned j = idx & 255;
    unsigned bv = idx >> 8;
    unsigned b = bv / V;
    unsigned v = bv - b * V;
    const float4v* src = (const float4v*)(x + idx);
    float4v f0 = src[0], f1 = src[1];
    u16x8 o;
    o[0] = f2bf(f0[0]); o[1] = f2bf(f0[1]); o[2] = f2bf(f0[2]); o[3] = f2bf(f0[3]);
    o[4] = f2bf(f1[0]); o[5] = f2bf(f1[1]); o[6] = f2bf(f1[2]); o[7] = f2bf(f1[3]);
    *(u16x8*)(x0b + v * 1024 + b * 256 + j) = o;
}

// ---------------- padded-CSR build in one pass ----------------
__global__ __launch_bounds__(256)
void scatter_kernel(const int* __restrict__ rows, const int* __restrict__ cols,
                    const float* __restrict__ vals, int* __restrict__ cnt,
                    int* __restrict__ csr_c, float* __restrict__ csr_v) {
    int e = blockIdx.x * 256 + threadIdx.x;
    if (e >= NNZ) return;
    int r = rows[e];
    int slot = atomicAdd(&cnt[r], 1);
    if (slot < SLOTS) {
        csr_c[r * SLOTS + slot] = cols[e];
        csr_v[r * SLOTS + slot] = vals[e];
    }
}

// ---------------- SpMM 1: x1 = L @ x0 ----------------
__global__ __launch_bounds__(256)
void spmm1_kernel(const unsigned short* __restrict__ x0b, const int* __restrict__ cnt,
                  const int* __restrict__ csr_c, const float* __restrict__ csr_v,
                  unsigned short* __restrict__ x1b) {
    int r = blockIdx.x;
    int j = threadIdx.x * 4;
    int n = min(cnt[r], SLOTS);
    const int* cc = csr_c + r * SLOTS;
    const float* cv = csr_v + r * SLOTS;
    float s0 = 0.f, s1 = 0.f, s2 = 0.f, s3 = 0.f;
    for (int e = 0; e < n; ++e) {
        int c = cc[e];
        float val = cv[e];
        u16x4 xv = *(const u16x4*)(x0b + c * 1024 + j);
        s0 = fmaf(val, bf2f(xv[0]), s0);
        s1 = fmaf(val, bf2f(xv[1]), s1);
        s2 = fmaf(val, bf2f(xv[2]), s2);
        s3 = fmaf(val, bf2f(xv[3]), s3);
    }
    u16x4 o;
    o[0] = f2bf(s0); o[1] = f2bf(s1); o[2] = f2bf(s2); o[3] = f2bf(s3);
    *(u16x4*)(x1b + r * 1024 + j) = o;
}

// ---------------- fused: spmm2 (x2 per v, in LDS) + dense MFMA + BN stats ----------------
// 64 v per block, 4 waves, wave handles one v per vi iteration.
template<int YBF>
__global__ __launch_bounds__(256)
void dense_kernel(const unsigned short* __restrict__ x0b, const unsigned short* __restrict__ x1b,
                  const int* __restrict__ cnt, const int* __restrict__ csr_c,
                  const float* __restrict__ csr_v, const float* __restrict__ W,
                  float* __restrict__ stats, unsigned short* __restrict__ yb,
                  float* __restrict__ yf) {
    __shared__ short wt[64 * 296];     // W^T: wt[o][k], pad 296 -> <=2-way banks
    __shared__ short x2l[4][1024];     // per-wave x2[v] slice
    __shared__ float sstat[128];

    for (int idx = threadIdx.x; idx < 288 * 64; idx += 256) {
        int k = idx >> 6, o = idx & 63;
        wt[o * 296 + k] = (short)f2bf(W[idx]);
    }
    if (threadIdx.x < 128) sstat[threadIdx.x] = 0.f;
    __syncthreads();

    const int wave = threadIdx.x >> 6;
    const int lane = threadIdx.x & 63;
    const int l15 = lane & 15, lhi = lane >> 4;
    const int f0 = lhi * 8;
    const int jb = lane * 16;

    float ssum[4] = {0.f, 0.f, 0.f, 0.f};
    float ssq[4]  = {0.f, 0.f, 0.f, 0.f};

    for (int vi = 0; vi < 16; ++vi) {
        const int v = blockIdx.x * 64 + vi * 4 + wave;

        // ---- phase A: x2[v] = 2*(L@x1)[v] - x0[v]  (wave-private, 16 elems/lane)
        {
            const int n = min(cnt[v], SLOTS);
            const int* cc = csr_c + v * SLOTS;
            const float* cv = csr_v + v * SLOTS;
            float s[16];
            #pragma unroll
            for (int i = 0; i < 16; ++i) s[i] = 0.f;
            for (int e = 0; e < n; ++e) {
                const int c = cc[e];
                const float val = cv[e];
                u16x8 a0 = *(const u16x8*)(x1b + c * 1024 + jb);
                u16x8 a1 = *(const u16x8*)(x1b + c * 1024 + jb + 8);
                #pragma unroll
                for (int i = 0; i < 8; ++i) {
                    s[i]     = fmaf(val, bf2f(a0[i]), s[i]);
                    s[8 + i] = fmaf(val, bf2f(a1[i]), s[8 + i]);
                }
            }
            u16x8 z0 = *(const u16x8*)(x0b + v * 1024 + jb);
            u16x8 z1 = *(const u16x8*)(x0b + v * 1024 + jb + 8);
            u16x8 o0, o1;
            #pragma unroll
            for (int i = 0; i < 8; ++i) {
                o0[i] = f2bf(2.f * s[i] - bf2f(z0[i]));
                o1[i] = f2bf(2.f * s[8 + i] - bf2f(z1[i]));
            }
            *(u16x8*)&x2l[wave][jb] = o0;
            *(u16x8*)&x2l[wave][jb + 8] = o1;
        }
        __syncthreads();   // x2l visible to all lanes of the wave (cross-lane via LDS)

        // ---- phase B: dense MFMA for this v
        bf16x8 afrag[2][9];
        #pragma unroll
        for (int mt = 0; mt < 2; ++mt) {
            const int m = mt * 16 + l15;
            const int b = m >> 3, t = m & 7;
            #pragma unroll
            for (int kc = 0; kc < 9; ++kc) {
                const int kk = kc / 3, tw = kc % 3;
                const int tp = t + tw - 1;
                bf16x8 a = {0, 0, 0, 0, 0, 0, 0, 0};
                if ((unsigned)tp < 8u) {
                    if (kk == 0)      a = *(const bf16x8*)(x0b + v * 1024 + b * 256 + tp * 32 + f0);
                    else if (kk == 1) a = *(const bf16x8*)(x1b + v * 1024 + b * 256 + tp * 32 + f0);
                    else              a = *(const bf16x8*)&x2l[wave][b * 256 + tp * 32 + f0];
                }
                afrag[mt][kc] = a;
            }
        }
        f32x4 acc[2][4];
        #pragma unroll
        for (int mt = 0; mt < 2; ++mt)
            #pragma unroll
            for (int nt = 0; nt < 4; ++nt)
                acc[mt][nt] = (f32x4){0.f, 0.f, 0.f, 0.f};

        #pragma unroll
        for (int kc = 0; kc < 9; ++kc) {
            #pragma unroll
            for (int nt = 0; nt < 4; ++nt) {
                const int nrow = nt * 16 + l15;
                bf16x8 bfrag = *(const bf16x8*)&wt[nrow * 296 + kc * 32 + f0];
                #pragma unroll
                for (int mt = 0; mt < 2; ++mt)
                    acc[mt][nt] = __builtin_amdgcn_mfma_f32_16x16x32_bf16(
                        afrag[mt][kc], bfrag, acc[mt][nt], 0, 0, 0);
            }
        }

        // ---- epilogue: y store + stats partials (bias cancels under BN)
        #pragma unroll
        for (int mt = 0; mt < 2; ++mt)
            #pragma unroll
            for (int nt = 0; nt < 4; ++nt)
                #pragma unroll
                for (int i = 0; i < 4; ++i) {
                    const int m = mt * 16 + lhi * 4 + i;
                    const int b = m >> 3, t = m & 7;
                    const int col = nt * 16 + l15;
                    const float val = acc[mt][nt][i];
                    ssum[nt] += val;
                    ssq[nt]  += val * val;
                    const int idx = ((b * V + v) * 8 + t) * 64 + col;
                    if (YBF) yb[idx] = f2bf(val);
                    else     yf[idx] = val;
                }
        __syncthreads();   // protect x2l against next iteration's overwrite
    }

    #pragma unroll
    for (int nt = 0; nt < 4; ++nt) {
        const int col = nt * 16 + l15;
        atomicAdd(&sstat[col], ssum[nt]);
        atomicAdd(&sstat[64 + col], ssq[nt]);
    }
    __syncthreads();
    if (threadIdx.x < 128) atomicAdd(&stats[threadIdx.x], sstat[threadIdx.x]);
}

// ---------------- fold mean/var/gamma/beta -> scale/shift ----------------
__global__ __launch_bounds__(64)
void finalize_kernel(const float* __restrict__ gamma, const float* __restrict__ beta,
                     float* __restrict__ stats) {
    int o = threadIdx.x;
    float n = (float)(B * V * T);
    float mean = stats[o] / n;
    float var = stats[64 + o] / n - mean * mean;
    float sc = gamma[o] * rsqrtf(var + EPS);
    stats[128 + o] = sc;
    stats[192 + o] = beta[o] - mean * sc;
}

// ---------------- normalize + ReLU ----------------
template<int YBF>
__global__ __launch_bounds__(256)
void norm_kernel(const unsigned short* __restrict__ yb, float* __restrict__ out,
                 const float* __restrict__ stats) {
    const int total = B * V * T * 64;
    if (YBF) {
        const int start = (blockIdx.x * 256 + threadIdx.x) * 8;
        const int ob = start & 63;     // stride (gridDim*2048*... ) keeps ob constant per thread
        float sc[8], sh[8];
        #pragma unroll
        for (int c = 0; c < 8; ++c) { sc[c] = stats[128 + ob + c]; sh[c] = stats[192 + ob + c]; }
        for (int i0 = start; i0 < total; i0 += gridDim.x * 256 * 8) {
            u16x8 yv = *(const u16x8*)(yb + i0);
            float4v r0, r1;
            #pragma unroll
            for (int c = 0; c < 8; ++c) {
                float val = fmaxf(bf2f(yv[c]) * sc[c] + sh[c], 0.f);
                if (c < 4) r0[c] = val; else r1[c - 4] = val;
            }
            *(float4v*)(out + i0) = r0;
            *(float4v*)(out + i0 + 4) = r1;
        }
    } else {
        const int start = (blockIdx.x * 256 + threadIdx.x) * 4;
        const int ob = start & 63;
        float sc[4], sh[4];
        #pragma unroll
        for (int c = 0; c < 4; ++c) { sc[c] = stats[128 + ob + c]; sh[c] = stats[192 + ob + c]; }
        for (int i0 = start; i0 < total; i0 += gridDim.x * 256 * 4) {
            float4v v4 = *(float4v*)(out + i0);
            #pragma unroll
            for (int c = 0; c < 4; ++c)
                v4[c] = fmaxf(v4[c] * sc[c] + sh[c], 0.f);
            *(float4v*)(out + i0) = v4;
        }
    }
}

extern "C" void kernel_launch(void* const* d_in, const int* in_sizes, int n_in,
                              void* d_out, int out_size, void* d_ws, size_t ws_size,
                              hipStream_t stream) {
    const float* x        = (const float*)d_in[0];
    const float* lap_vals = (const float*)d_in[1];
    const float* W        = (const float*)d_in[2];
    // d_in[3] = bias: cancels exactly under training-mode BN
    const float* gamma    = (const float*)d_in[4];
    const float* beta     = (const float*)d_in[5];
    const int*   rows     = (const int*)d_in[6];
    const int*   cols     = (const int*)d_in[7];
    float* out = (float*)d_out;
    char*  ws  = (char*)d_ws;

    float*          stats = (float*)(ws + STATS_OFF);
    int*            cnt   = (int*)(ws + CNT_OFF);
    int*            csr_c = (int*)(ws + CSRC_OFF);
    float*          csr_v = (float*)(ws + CSRV_OFF);
    unsigned short* x0b   = (unsigned short*)(ws + X0B_OFF);
    unsigned short* x1b   = (unsigned short*)(ws + X1B_OFF);
    unsigned short* ybp   = (unsigned short*)(ws + YB_OFF);

    const bool ybf = (ws_size >= (size_t)WS_NEED_YB);

    hipMemsetAsync(ws + STATS_OFF, 0, (size_t)CSRC_OFF, stream);

    convert_kernel<<<24576, 256, 0, stream>>>(x, x0b);
    scatter_kernel<<<(NNZ + 255) / 256, 256, 0, stream>>>(rows, cols, lap_vals, cnt, csr_c, csr_v);
    spmm1_kernel<<<V, 256, 0, stream>>>(x0b, cnt, csr_c, csr_v, x1b);
    if (ybf) dense_kernel<1><<<V / 64, 256, 0, stream>>>(x0b, x1b, cnt, csr_c, csr_v, W, stats, ybp, nullptr);
    else     dense_kernel<0><<<V / 64, 256, 0, stream>>>(x0b, x1b, cnt, csr_c, csr_v, W, stats, nullptr, out);
    finalize_kernel<<<1, 64, 0, stream>>>(gamma, beta, stats);
    if (ybf) norm_kernel<1><<<4096, 256, 0, stream>>>(ybp, out, stats);
    else     norm_kernel<0><<<4096, 256, 0, stream>>>(nullptr, out, stats);
}

// Round 4
// 573.749 us; speedup vs baseline: 10.5223x; 1.3450x over previous
//
#include <hip/hip_runtime.h>

#define V 49152
#define B 4
#define T 8
#define NNZ (9 * V)
#define EPS 1e-5f
#define SLOTS 32

typedef __attribute__((ext_vector_type(8))) short bf16x8;
typedef __attribute__((ext_vector_type(4))) float f32x4;
typedef __attribute__((ext_vector_type(4))) float float4v;
typedef __attribute__((ext_vector_type(8))) unsigned short u16x8;
typedef __attribute__((ext_vector_type(4))) unsigned short u16x4;

// ---------------- ws layout (bytes) ----------------
#define STATS_OFF 0LL          // 256 floats: sum[64]|sumsq[64]|scale[64]|shift[64]
#define CNT_OFF   1024LL       // V ints
#define CSRC_OFF  197632LL     // V*SLOTS ints
#define CSRV_OFF  6489088LL    // V*SLOTS floats
#define X0B_OFF   12780544LL   // V*1024 bf16   (memset zeroes [0, X0B_OFF): stats,cnt,csr pads)
#define X1B_OFF   113443840LL  // V*1024 bf16
#define YB_OFF    214107136LL  // B*V*T*64 bf16 (only if ws is big enough)
#define WS_NEED_YB 415433728LL

__device__ inline unsigned short f2bf(float f) {
    unsigned u = __builtin_bit_cast(unsigned, f);
    u += 0x7fffu + ((u >> 16) & 1u);
    return (unsigned short)(u >> 16);
}
__device__ inline float bf2f(unsigned short h) {
    return __builtin_bit_cast(float, ((unsigned)h) << 16);
}
// wave-local LDS sync: DS ops complete in-order per wave; this waits for this
// wave's own ds_writes, and the "memory" clobber stops compiler reordering.
__device__ inline void wave_lds_sync() {
    asm volatile("s_waitcnt lgkmcnt(0)" ::: "memory");
}

// ---------------- convert x fp32 [B][V][T*F] -> bf16 [V][B][T*F] ----------------
__global__ __launch_bounds__(256)
void convert_kernel(const float* __restrict__ x, unsigned short* __restrict__ x0b) {
    unsigned gid = blockIdx.x * 256 + threadIdx.x;
    unsigned idx = gid * 8;
    unsigned j = idx & 255;
    unsigned bv = idx >> 8;
    unsigned b = bv / V;
    unsigned v = bv - b * V;
    const float4v* src = (const float4v*)(x + idx);
    float4v f0 = src[0], f1 = src[1];
    u16x8 o;
    o[0] = f2bf(f0[0]); o[1] = f2bf(f0[1]); o[2] = f2bf(f0[2]); o[3] = f2bf(f0[3]);
    o[4] = f2bf(f1[0]); o[5] = f2bf(f1[1]); o[6] = f2bf(f1[2]); o[7] = f2bf(f1[3]);
    *(u16x8*)(x0b + v * 1024 + b * 256 + j) = o;
}

// ---------------- padded-CSR build in one pass (pad slots stay 0 from memset) ----------------
__global__ __launch_bounds__(256)
void scatter_kernel(const int* __restrict__ rows, const int* __restrict__ cols,
                    const float* __restrict__ vals, int* __restrict__ cnt,
                    int* __restrict__ csr_c, float* __restrict__ csr_v) {
    int e = blockIdx.x * 256 + threadIdx.x;
    if (e >= NNZ) return;
    int r = rows[e];
    int slot = atomicAdd(&cnt[r], 1);
    if (slot < SLOTS) {
        csr_c[r * SLOTS + slot] = cols[e];
        csr_v[r * SLOTS + slot] = vals[e];
    }
}

// ---------------- SpMM 1: x1 = L @ x0 (chunk-8 unrolled gathers) ----------------
__global__ __launch_bounds__(256)
void spmm1_kernel(const unsigned short* __restrict__ x0b, const int* __restrict__ cnt,
                  const int* __restrict__ csr_c, const float* __restrict__ csr_v,
                  unsigned short* __restrict__ x1b) {
    int r = blockIdx.x;
    int j = threadIdx.x * 4;
    int n8 = (min(cnt[r], SLOTS) + 7) & ~7;
    const int* cc = csr_c + r * SLOTS;
    const float* cv = csr_v + r * SLOTS;
    float s0 = 0.f, s1 = 0.f, s2 = 0.f, s3 = 0.f;
    for (int e0 = 0; e0 < n8; e0 += 8) {
        #pragma unroll
        for (int u = 0; u < 8; ++u) {
            int c = cc[e0 + u];          // pad: c=0, val=0 -> contributes nothing
            float val = cv[e0 + u];
            u16x4 xv = *(const u16x4*)(x0b + c * 1024 + j);
            s0 = fmaf(val, bf2f(xv[0]), s0);
            s1 = fmaf(val, bf2f(xv[1]), s1);
            s2 = fmaf(val, bf2f(xv[2]), s2);
            s3 = fmaf(val, bf2f(xv[3]), s3);
        }
    }
    u16x4 o;
    o[0] = f2bf(s0); o[1] = f2bf(s1); o[2] = f2bf(s2); o[3] = f2bf(s3);
    *(u16x4*)(x1b + r * 1024 + j) = o;
}

// ---------------- fused: spmm2 (x2 per v, wave-private LDS) + dense MFMA + BN stats ----------------
// 64 v per block, 4 waves; no block barriers inside the vi loop.
template<int YBF>
__global__ __launch_bounds__(256, 3)
void dense_kernel(const unsigned short* __restrict__ x0b, const unsigned short* __restrict__ x1b,
                  const int* __restrict__ cnt, const int* __restrict__ csr_c,
                  const float* __restrict__ csr_v, const float* __restrict__ W,
                  float* __restrict__ stats, unsigned short* __restrict__ yb,
                  float* __restrict__ yf) {
    __shared__ short wt[64 * 296];     // W^T: wt[o][k], pad 296 -> <=2-way banks
    __shared__ short x2l[4][1024];     // per-wave x2[v] slice (wave-private!)
    __shared__ float sstat[128];

    for (int idx = threadIdx.x; idx < 288 * 64; idx += 256) {
        int k = idx >> 6, o = idx & 63;
        wt[o * 296 + k] = (short)f2bf(W[idx]);
    }
    if (threadIdx.x < 128) sstat[threadIdx.x] = 0.f;
    __syncthreads();   // the only block barrier

    const int wave = threadIdx.x >> 6;
    const int lane = threadIdx.x & 63;
    const int l15 = lane & 15, lhi = lane >> 4;
    const int f0 = lhi * 8;
    const int jb = lane * 16;

    float ssum[4] = {0.f, 0.f, 0.f, 0.f};
    float ssq[4]  = {0.f, 0.f, 0.f, 0.f};

    for (int vi = 0; vi < 16; ++vi) {
        const int v = blockIdx.x * 64 + vi * 4 + wave;

        // ---- issue x0/x1 A-fragment loads early (independent of the gather) ----
        bf16x8 afrag[2][9];
        #pragma unroll
        for (int mt = 0; mt < 2; ++mt) {
            const int m = mt * 16 + l15;
            const int b = m >> 3, t = m & 7;
            #pragma unroll
            for (int kc = 0; kc < 6; ++kc) {
                const int kk = kc / 3, tw = kc % 3;
                const int tp = t + tw - 1;
                bf16x8 a = {0, 0, 0, 0, 0, 0, 0, 0};
                if ((unsigned)tp < 8u) {
                    const unsigned short* src = (kk == 0) ? x0b : x1b;
                    a = *(const bf16x8*)(src + v * 1024 + b * 256 + tp * 32 + f0);
                }
                afrag[mt][kc] = a;
            }
        }

        // ---- phase A: x2[v] = 2*(L@x1)[v] - x0[v]  (chunk-4 unrolled gathers) ----
        {
            const int n4 = (min(cnt[v], SLOTS) + 3) & ~3;
            const int* cc = csr_c + v * SLOTS;
            const float* cv = csr_v + v * SLOTS;
            float s[16];
            #pragma unroll
            for (int i = 0; i < 16; ++i) s[i] = 0.f;
            for (int e0 = 0; e0 < n4; e0 += 4) {
                #pragma unroll
                for (int u = 0; u < 4; ++u) {
                    const int c = cc[e0 + u];
                    const float val = cv[e0 + u];
                    u16x8 a0 = *(const u16x8*)(x1b + c * 1024 + jb);
                    u16x8 a1 = *(const u16x8*)(x1b + c * 1024 + jb + 8);
                    #pragma unroll
                    for (int i = 0; i < 8; ++i) {
                        s[i]     = fmaf(val, bf2f(a0[i]), s[i]);
                        s[8 + i] = fmaf(val, bf2f(a1[i]), s[8 + i]);
                    }
                }
            }
            u16x8 z0 = *(const u16x8*)(x0b + v * 1024 + jb);
            u16x8 z1 = *(const u16x8*)(x0b + v * 1024 + jb + 8);
            u16x8 o0, o1;
            #pragma unroll
            for (int i = 0; i < 8; ++i) {
                o0[i] = f2bf(2.f * s[i] - bf2f(z0[i]));
                o1[i] = f2bf(2.f * s[8 + i] - bf2f(z1[i]));
            }
            *(u16x8*)&x2l[wave][jb] = o0;
            *(u16x8*)&x2l[wave][jb + 8] = o1;
        }
        wave_lds_sync();   // wave's own ds_writes complete; DS in-order per wave

        // ---- x2 A-fragments from wave-private LDS ----
        #pragma unroll
        for (int mt = 0; mt < 2; ++mt) {
            const int m = mt * 16 + l15;
            const int b = m >> 3, t = m & 7;
            #pragma unroll
            for (int kc = 6; kc < 9; ++kc) {
                const int tw = kc % 3;
                const int tp = t + tw - 1;
                bf16x8 a = {0, 0, 0, 0, 0, 0, 0, 0};
                if ((unsigned)tp < 8u)
                    a = *(const bf16x8*)&x2l[wave][b * 256 + tp * 32 + f0];
                afrag[mt][kc] = a;
            }
        }

        // ---- phase B: MFMA ----
        f32x4 acc[2][4];
        #pragma unroll
        for (int mt = 0; mt < 2; ++mt)
            #pragma unroll
            for (int nt = 0; nt < 4; ++nt)
                acc[mt][nt] = (f32x4){0.f, 0.f, 0.f, 0.f};

        #pragma unroll
        for (int kc = 0; kc < 9; ++kc) {
            #pragma unroll
            for (int nt = 0; nt < 4; ++nt) {
                const int nrow = nt * 16 + l15;
                bf16x8 bfrag = *(const bf16x8*)&wt[nrow * 296 + kc * 32 + f0];
                #pragma unroll
                for (int mt = 0; mt < 2; ++mt)
                    acc[mt][nt] = __builtin_amdgcn_mfma_f32_16x16x32_bf16(
                        afrag[mt][kc], bfrag, acc[mt][nt], 0, 0, 0);
            }
        }

        // ---- epilogue: y store + stats partials (bias cancels under BN) ----
        #pragma unroll
        for (int mt = 0; mt < 2; ++mt)
            #pragma unroll
            for (int nt = 0; nt < 4; ++nt)
                #pragma unroll
                for (int i = 0; i < 4; ++i) {
                    const int m = mt * 16 + lhi * 4 + i;
                    const int b = m >> 3, t = m & 7;
                    const int col = nt * 16 + l15;
                    const float val = acc[mt][nt][i];
                    ssum[nt] += val;
                    ssq[nt]  += val * val;
                    const int idx = ((b * V + v) * 8 + t) * 64 + col;
                    if (YBF) yb[idx] = f2bf(val);
                    else     yf[idx] = val;
                }
        // next vi's x2l writes are ordered after this vi's x2l reads (in-order DS per wave)
    }

    #pragma unroll
    for (int nt = 0; nt < 4; ++nt) {
        const int col = nt * 16 + l15;
        atomicAdd(&sstat[col], ssum[nt]);
        atomicAdd(&sstat[64 + col], ssq[nt]);
    }
    __syncthreads();
    if (threadIdx.x < 128) atomicAdd(&stats[threadIdx.x], sstat[threadIdx.x]);
}

// ---------------- fold mean/var/gamma/beta -> scale/shift ----------------
__global__ __launch_bounds__(64)
void finalize_kernel(const float* __restrict__ gamma, const float* __restrict__ beta,
                     float* __restrict__ stats) {
    int o = threadIdx.x;
    float n = (float)(B * V * T);
    float mean = stats[o] / n;
    float var = stats[64 + o] / n - mean * mean;
    float sc = gamma[o] * rsqrtf(var + EPS);
    stats[128 + o] = sc;
    stats[192 + o] = beta[o] - mean * sc;
}

// ---------------- normalize + ReLU ----------------
template<int YBF>
__global__ __launch_bounds__(256)
void norm_kernel(const unsigned short* __restrict__ yb, float* __restrict__ out,
                 const float* __restrict__ stats) {
    const int total = B * V * T * 64;
    if (YBF) {
        const int start = (blockIdx.x * 256 + threadIdx.x) * 8;
        const int ob = start & 63;
        float sc[8], sh[8];
        #pragma unroll
        for (int c = 0; c < 8; ++c) { sc[c] = stats[128 + ob + c]; sh[c] = stats[192 + ob + c]; }
        for (int i0 = start; i0 < total; i0 += gridDim.x * 256 * 8) {
            u16x8 yv = *(const u16x8*)(yb + i0);
            float4v r0, r1;
            #pragma unroll
            for (int c = 0; c < 8; ++c) {
                float val = fmaxf(bf2f(yv[c]) * sc[c] + sh[c], 0.f);
                if (c < 4) r0[c] = val; else r1[c - 4] = val;
            }
            *(float4v*)(out + i0) = r0;
            *(float4v*)(out + i0 + 4) = r1;
        }
    } else {
        const int start = (blockIdx.x * 256 + threadIdx.x) * 4;
        const int ob = start & 63;
        float sc[4], sh[4];
        #pragma unroll
        for (int c = 0; c < 4; ++c) { sc[c] = stats[128 + ob + c]; sh[c] = stats[192 + ob + c]; }
        for (int i0 = start; i0 < total; i0 += gridDim.x * 256 * 4) {
            float4v v4 = *(float4v*)(out + i0);
            #pragma unroll
            for (int c = 0; c < 4; ++c)
                v4[c] = fmaxf(v4[c] * sc[c] + sh[c], 0.f);
            *(float4v*)(out + i0) = v4;
        }
    }
}

extern "C" void kernel_launch(void* const* d_in, const int* in_sizes, int n_in,
                              void* d_out, int out_size, void* d_ws, size_t ws_size,
                              hipStream_t stream) {
    const float* x        = (const float*)d_in[0];
    const float* lap_vals = (const float*)d_in[1];
    const float* W        = (const float*)d_in[2];
    // d_in[3] = bias: cancels exactly under training-mode BN
    const float* gamma    = (const float*)d_in[4];
    const float* beta     = (const float*)d_in[5];
    const int*   rows     = (const int*)d_in[6];
    const int*   cols     = (const int*)d_in[7];
    float* out = (float*)d_out;
    char*  ws  = (char*)d_ws;

    float*          stats = (float*)(ws + STATS_OFF);
    int*            cnt   = (int*)(ws + CNT_OFF);
    int*            csr_c = (int*)(ws + CSRC_OFF);
    float*          csr_v = (float*)(ws + CSRV_OFF);
    unsigned short* x0b   = (unsigned short*)(ws + X0B_OFF);
    unsigned short* x1b   = (unsigned short*)(ws + X1B_OFF);
    unsigned short* ybp   = (unsigned short*)(ws + YB_OFF);

    const bool ybf = (ws_size >= (size_t)WS_NEED_YB);

    // zero stats + cnt + csr arrays (csr zero-fill makes padded slots inert)
    hipMemsetAsync(ws + STATS_OFF, 0, (size_t)X0B_OFF, stream);

    convert_kernel<<<24576, 256, 0, stream>>>(x, x0b);
    scatter_kernel<<<(NNZ + 255) / 256, 256, 0, stream>>>(rows, cols, lap_vals, cnt, csr_c, csr_v);
    spmm1_kernel<<<V, 256, 0, stream>>>(x0b, cnt, csr_c, csr_v, x1b);
    if (ybf) dense_kernel<1><<<V / 64, 256, 0, stream>>>(x0b, x1b, cnt, csr_c, csr_v, W, stats, ybp, nullptr);
    else     dense_kernel<0><<<V / 64, 256, 0, stream>>>(x0b, x1b, cnt, csr_c, csr_v, W, stats, nullptr, out);
    finalize_kernel<<<1, 64, 0, stream>>>(gamma, beta, stats);
    if (ybf) norm_kernel<1><<<4096, 256, 0, stream>>>(ybp, out, stats);
    else     norm_kernel<0><<<4096, 256, 0, stream>>>(nullptr, out, stats);
}